// Round 3
// baseline (531.040 us; speedup 1.0000x reference)
//
#include <hip/hip_runtime.h>
#include <hip/hip_bf16.h>

// dendriticNet fused kernel, round 3: software-pipelined LDS streaming.
// Post-mortem r0/r2: both stuck at ~1.5 TB/s HBM (19%) -> latency-bound,
// not occupancy-bound. r0's __syncthreads drained vmcnt(0) (stage loads
// issued AFTER barrier, consumed immediately); r2's direct-global gemms
// put HBM latency inside the inner loop. Fix (T3/T4/T14):
//   - all gemm A-operands from LDS bf16 tiles (fast inner loop, r0-style)
//   - ONE streaming tile; next tile's global loads issued a FULL PHASE
//     early into registers, committed (tanh+pack+ds_write) between two
//     raw s_barriers that fence ONLY lgkmcnt -> global loads stay in
//     flight across barriers (never vmcnt(0) mid-kernel)
//   - stream order rd,ri0,rs2,ri1,rs0 makes each output's gemms
//     contiguous; rs1 stays resident (3 uses); A-gemms+epilogues fill
//     the load-latency windows.
//
// out_s0 = 0.81*s0 + rd@(0.1 wpf0)^T + rs1@(0.08 wpb0)^T + ri0@(0.08 wpi0)^T
// out_i0 = 0.81*i0 + rs0@(0.1 wip0)^T + 0.08*mean_row(rs1)
// out_s1 = 0.81*s1 + rs0@(0.1 wpf1)^T + rs2@(0.08 wpb1)^T + ri1@(0.08 wpi1)^T
// out_i1 = 0.81*i1 + rs1@(0.1 wip1)^T + 0.08*mean_row(rs2)
// out_s2 = 0.89*s2 + rs1@(0.1 wpf2)^T

#define HH 256
#define BM 32
#define ROWP 264                    // padded LDS row (bf16 elems)
#define TILE_ELEMS (BM * ROWP)      // 16896 B per tile
#define BHTOT ((size_t)32768 * 256)

typedef __bf16 bf16_t;
typedef __bf16 bf16x8 __attribute__((ext_vector_type(8)));
typedef float  f32x4  __attribute__((ext_vector_type(4)));

// lgkm-only fence + barrier: does NOT drain vmcnt -> in-flight global
// stage loads survive the barrier (the whole point of this round).
#define BARX() do { asm volatile("s_waitcnt lgkmcnt(0)" ::: "memory"); \
                    __builtin_amdgcn_s_barrier(); } while (0)

__device__ __forceinline__ float fast_tanh(float x) {
    float e = __expf(2.0f * x);
    return 1.0f - 2.0f * __builtin_amdgcn_rcpf(e + 1.0f);
}

// Issue the global loads for one BM x 256 tile (wave rows wv, wv+4, ...).
// Results land in pv[8] (32 VGPR) and are consumed by stage_commit later.
__device__ __forceinline__ void stage_issue(const float* __restrict__ src,
                                            int row0, int lane, int wv,
                                            float4 pv[8]) {
#pragma unroll
    for (int it = 0; it < 8; ++it) {
        int row = wv + it * 4;
        pv[it] = *reinterpret_cast<const float4*>(
            src + (size_t)(row0 + row) * HH + lane * 4);
    }
}

// tanh + pack + LDS write of a previously-issued tile; optional
// 0.08*mean_row into nudge[0..31]. Compiler inserts the vmcnt waits for pv.
__device__ __forceinline__ void stage_commit(bf16_t* __restrict__ dst,
                                             int lane, int wv,
                                             const float4 pv[8],
                                             float* __restrict__ nudge) {
#pragma unroll
    for (int it = 0; it < 8; ++it) {
        int row = wv + it * 4;
        float t0 = fast_tanh(pv[it].x), t1 = fast_tanh(pv[it].y);
        float t2 = fast_tanh(pv[it].z), t3 = fast_tanh(pv[it].w);
        union { bf16_t b[4]; unsigned long long u; } pk;
        pk.b[0] = (bf16_t)t0; pk.b[1] = (bf16_t)t1;
        pk.b[2] = (bf16_t)t2; pk.b[3] = (bf16_t)t3;
        *reinterpret_cast<unsigned long long*>(dst + row * ROWP + lane * 4) = pk.u;
        if (nudge) {
            float s = (t0 + t1) + (t2 + t3);
            s += __shfl_down(s, 32);
            s += __shfl_down(s, 16);
            s += __shfl_down(s, 8);
            s += __shfl_down(s, 4);
            s += __shfl_down(s, 2);
            s += __shfl_down(s, 1);
            if (lane == 0) nudge[row] = s * (0.08f / 256.0f);  // DT*GSOM*mean
        }
    }
}

// K=256 GEMM segment from LDS: acc(32 x [64-col slice]) += tile @ Wg^T.
// A-frag: A[m=lane&15][k=(lane>>4)*8+j]; B-frag: B[k][n=lane&15].
__device__ __forceinline__ void gemm_lds(const bf16_t* __restrict__ sa,
                                         const bf16_t* __restrict__ wg,
                                         int lane, int wv, f32x4 acc[2][4]) {
    const int r = lane & 15, q = lane >> 4;
    const bf16_t* a0p = sa + r * ROWP + q * 8;
    const bf16_t* a1p = a0p + 16 * ROWP;
    const bf16_t* bp  = wg + (size_t)(wv * 64 + r) * HH + q * 8;
#pragma unroll 2
    for (int k0 = 0; k0 < HH; k0 += 32) {
        bf16x8 a0 = *reinterpret_cast<const bf16x8*>(a0p + k0);
        bf16x8 a1 = *reinterpret_cast<const bf16x8*>(a1p + k0);
#pragma unroll
        for (int nt = 0; nt < 4; ++nt) {
            bf16x8 b = *reinterpret_cast<const bf16x8*>(bp + nt * 16 * HH + k0);
            acc[0][nt] = __builtin_amdgcn_mfma_f32_16x16x32_bf16(a0, b, acc[0][nt], 0, 0, 0);
            acc[1][nt] = __builtin_amdgcn_mfma_f32_16x16x32_bf16(a1, b, acc[1][nt], 0, 0, 0);
        }
    }
}

// out = acc + c*raw (+ nl[m*4+rg]); C-frag: col=lane&15, row=(lane>>4)*4+reg.
__device__ __forceinline__ void epilogue(f32x4 acc[2][4], const float* __restrict__ raw,
                                         float* __restrict__ outp, int row0, int lane, int wv,
                                         float c, const float* __restrict__ nl) {
    const int cb = lane & 15, q = lane >> 4;
#pragma unroll
    for (int m = 0; m < 2; ++m) {
#pragma unroll
        for (int nt = 0; nt < 4; ++nt) {
            int col = wv * 64 + nt * 16 + cb;
#pragma unroll
            for (int rg = 0; rg < 4; ++rg) {
                int lrow = m * 16 + q * 4 + rg;
                size_t idx = (size_t)(row0 + lrow) * HH + col;
                float v = acc[m][nt][rg] + c * raw[idx];
                if (nl) v += nl[m * 4 + rg];
                outp[idx] = v;
            }
        }
    }
}

struct WPtrs { const float* p[9]; };

// Pre-scale + convert the 9 weight matrices to bf16 into d_ws.
// order g: 0 wpf0(.1) 1 wpf1(.1) 2 wpf2(.1) 3 wpb0(.08) 4 wpb1(.08)
//          5 wip0(.1) 6 wip1(.1) 7 wpi0(.08) 8 wpi1(.08)
__global__ void prep_w(WPtrs wp, bf16_t* __restrict__ out) {
    const float scales[9] = {0.1f, 0.1f, 0.1f, 0.08f, 0.08f, 0.1f, 0.1f, 0.08f, 0.08f};
    int g  = blockIdx.x >> 6;
    int bi = blockIdx.x & 63;
    float sc = scales[g];
    int idx = (bi * 256 + threadIdx.x) * 4;
    float4 v = *reinterpret_cast<const float4*>(wp.p[g] + idx);
    union { bf16_t b[4]; unsigned long long u; } pk;
    pk.b[0] = (bf16_t)(v.x * sc); pk.b[1] = (bf16_t)(v.y * sc);
    pk.b[2] = (bf16_t)(v.z * sc); pk.b[3] = (bf16_t)(v.w * sc);
    *reinterpret_cast<unsigned long long*>(out + (size_t)g * 65536 + idx) = pk.u;
}

#define ZACC(A_)                                                               \
    do {                                                                       \
        _Pragma("unroll")                                                      \
        for (int m_ = 0; m_ < 2; ++m_)                                         \
            _Pragma("unroll")                                                  \
            for (int nt_ = 0; nt_ < 4; ++nt_) A_[m_][nt_] = z;                 \
    } while (0)

__global__ __launch_bounds__(256, 4) void dendritic_main(
    const float* __restrict__ data, const float* __restrict__ s0,
    const float* __restrict__ s1,   const float* __restrict__ s2,
    const float* __restrict__ i0,   const float* __restrict__ i1,
    const bf16_t* __restrict__ wws, float* __restrict__ out)
{
    __shared__ bf16_t slA[TILE_ELEMS];   // rs1, resident all kernel (3 uses)
    __shared__ bf16_t slB[TILE_ELEMS];   // streaming: rd, ri0, rs2, ri1, rs0
    __shared__ float  sn0[32];           // 0.08*mean_row(rs1)
    __shared__ float  sn1[32];           // 0.08*mean_row(rs2)

    const int tid = threadIdx.x, lane = tid & 63, wv = tid >> 6;
    const int row0 = blockIdx.x * BM;
    const int q = lane >> 4;

    // ---- prologue: stage rs1 -> slA (+n0) and rd -> slB; one big load burst
    {
        float4 pA[8], pB[8];
        stage_issue(s1,   row0, lane, wv, pA);
        stage_issue(data, row0, lane, wv, pB);
        stage_commit(slA, lane, wv, pA, sn0);
        stage_commit(slB, lane, wv, pB, nullptr);
    }
    __syncthreads();

    f32x4 accW[2][4], acc2[2][4];
    const f32x4 z = {0.f, 0.f, 0.f, 0.f};
    float4 pv[8];

    // ================= phase 1: slB = rd =================
    stage_issue(i0, row0, lane, wv, pv);                  // next tile in flight
    ZACC(accW);
    gemm_lds(slB, wws + 0 * 65536, lane, wv, accW);       // rd  @ wpf0
    gemm_lds(slA, wws + 3 * 65536, lane, wv, accW);       // rs1 @ wpb0
    BARX();
    stage_commit(slB, lane, wv, pv, nullptr);             // slB = ri0
    BARX();

    // ================= phase 2: slB = ri0 =================
    stage_issue(s2, row0, lane, wv, pv);
    gemm_lds(slB, wws + 7 * 65536, lane, wv, accW);       // ri0 @ wpi0
    epilogue(accW, s0, out + 0 * BHTOT, row0, lane, wv, 0.81f, nullptr);  // out_s0
    BARX();
    stage_commit(slB, lane, wv, pv, sn1);                 // slB = rs2, n1
    BARX();

    // ================= phase 3: slB = rs2 =================
    stage_issue(i1, row0, lane, wv, pv);
    ZACC(accW);
    gemm_lds(slB, wws + 4 * 65536, lane, wv, accW);       // rs2 @ wpb1 (s1-acc)
    ZACC(acc2);
    gemm_lds(slA, wws + 6 * 65536, lane, wv, acc2);       // rs1 @ wip1
    {
        float nl1[8];
#pragma unroll
        for (int m = 0; m < 2; ++m)
#pragma unroll
            for (int rg = 0; rg < 4; ++rg) nl1[m * 4 + rg] = sn1[m * 16 + q * 4 + rg];
        epilogue(acc2, i1, out + 4 * BHTOT, row0, lane, wv, 0.81f, nl1);  // out_i1
    }
    BARX();
    stage_commit(slB, lane, wv, pv, nullptr);             // slB = ri1
    BARX();

    // ================= phase 4: slB = ri1 =================
    stage_issue(s0, row0, lane, wv, pv);
    gemm_lds(slB, wws + 8 * 65536, lane, wv, accW);       // ri1 @ wpi1 (s1-acc)
    ZACC(acc2);
    gemm_lds(slA, wws + 2 * 65536, lane, wv, acc2);       // rs1 @ wpf2
    epilogue(acc2, s2, out + 2 * BHTOT, row0, lane, wv, 0.89f, nullptr);  // out_s2
    BARX();
    stage_commit(slB, lane, wv, pv, nullptr);             // slB = rs0
    BARX();

    // ================= phase 5: slB = rs0 =================
    gemm_lds(slB, wws + 1 * 65536, lane, wv, accW);       // rs0 @ wpf1 (s1 done)
    epilogue(accW, s1, out + 1 * BHTOT, row0, lane, wv, 0.81f, nullptr);  // out_s1
    ZACC(acc2);
    gemm_lds(slB, wws + 5 * 65536, lane, wv, acc2);       // rs0 @ wip0
    {
        float nl0[8];
#pragma unroll
        for (int m = 0; m < 2; ++m)
#pragma unroll
            for (int rg = 0; rg < 4; ++rg) nl0[m * 4 + rg] = sn0[m * 16 + q * 4 + rg];
        epilogue(acc2, i0, out + 3 * BHTOT, row0, lane, wv, 0.81f, nl0);  // out_i0
    }
}

extern "C" void kernel_launch(void* const* d_in, const int* in_sizes, int n_in,
                              void* d_out, int out_size, void* d_ws, size_t ws_size,
                              hipStream_t stream) {
    const float* data = (const float*)d_in[0];
    const float* s0   = (const float*)d_in[1];
    const float* s1   = (const float*)d_in[2];
    const float* s2   = (const float*)d_in[3];
    const float* i0   = (const float*)d_in[4];
    const float* i1   = (const float*)d_in[5];

    WPtrs wp;
    for (int g = 0; g < 9; ++g) wp.p[g] = (const float*)d_in[6 + g];

    bf16_t* wws = (bf16_t*)d_ws;        // 9*65536*2 = 1,179,648 B of scratch
    float*  out = (float*)d_out;

    // convert + pre-scale weights (runs every call; d_ws re-poisoned each launch)
    prep_w<<<576, 256, 0, stream>>>(wp, wws);

    // fused main: 1024 blocks x 256 threads, ~34 KB static LDS -> 4 blocks/CU
    dendritic_main<<<1024, 256, 0, stream>>>(data, s0, s1, s2, i0, i1, wws, out);
}

// Round 4
// 452.488 us; speedup vs baseline: 1.1736x; 1.1736x over previous
//
#include <hip/hip_runtime.h>
#include <hip/hip_bf16.h>

// dendriticNet fused kernel, round 4.
// r3 post-mortem: pv[8] prefetch spilled to scratch (2 acc arrays = 64 AGPR
// + pv 32 > the 128-reg budget of launch_bounds(256,4)); WRITE_SIZE 205->300MB
// confirmed. Deeper issue shared by r0-r3: epilogue was 64 scalar-dword
// load->fma->store chains per wave (C-frag regs are ROW-strided).
// Round-4 fixes:
//  (1) SWAP MFMA OPERANDS: compute D = W_frag(A) x rho_frag(B). Fragment
//      reads are identical code; C layout becomes lane&15 = batch row,
//      reg = consecutive OUTPUT COLS -> epilogue is 8 dwordx4 loads +
//      8 dwordx4 stores per wave (8x fewer, batched, coalesced).
//  (2) ONE acc array live at any time; singles scheduled so pv(32)+acc(32)
//      +frags fits ~112 regs -> no spill at launch_bounds(256,4).
//  (3) keep r3's lgkm-only barriers (global prefetch stays in flight).
//
// out_s0 = 0.81*s0 + rd@(0.1 wpf0)^T + rs1@(0.08 wpb0)^T + ri0@(0.08 wpi0)^T
// out_i0 = 0.81*i0 + rs0@(0.1 wip0)^T + 0.08*mean_row(rs1)
// out_s1 = 0.81*s1 + rs0@(0.1 wpf1)^T + rs2@(0.08 wpb1)^T + ri1@(0.08 wpi1)^T
// out_i1 = 0.81*i1 + rs1@(0.1 wip1)^T + 0.08*mean_row(rs2)
// out_s2 = 0.89*s2 + rs1@(0.1 wpf2)^T

#define HH 256
#define BM 32
#define ROWP 264                    // padded LDS row (bf16 elems)
#define TILE_ELEMS (BM * ROWP)      // 16896 B per tile
#define BHTOT ((size_t)32768 * 256)

typedef __bf16 bf16_t;
typedef __bf16 bf16x8 __attribute__((ext_vector_type(8)));
typedef float  f32x4  __attribute__((ext_vector_type(4)));

// lgkm-only fence + barrier: does NOT drain vmcnt -> in-flight global
// stage loads survive the barrier.
#define BARX() do { asm volatile("s_waitcnt lgkmcnt(0)" ::: "memory"); \
                    __builtin_amdgcn_s_barrier(); } while (0)

__device__ __forceinline__ float fast_tanh(float x) {
    float e = __expf(2.0f * x);
    return 1.0f - 2.0f * __builtin_amdgcn_rcpf(e + 1.0f);
}

// Issue the global loads for one BM x 256 tile (wave rows wv, wv+4, ...).
__device__ __forceinline__ void stage_issue(const float* __restrict__ src,
                                            int row0, int lane, int wv,
                                            float4 pv[8]) {
#pragma unroll
    for (int it = 0; it < 8; ++it) {
        int row = wv + it * 4;
        pv[it] = *reinterpret_cast<const float4*>(
            src + (size_t)(row0 + row) * HH + lane * 4);
    }
}

// tanh + pack + LDS write of a previously-issued tile; optional
// 0.08*mean_row into nudge[0..31].
__device__ __forceinline__ void stage_commit(bf16_t* __restrict__ dst,
                                             int lane, int wv,
                                             const float4 pv[8],
                                             float* __restrict__ nudge) {
#pragma unroll
    for (int it = 0; it < 8; ++it) {
        int row = wv + it * 4;
        float t0 = fast_tanh(pv[it].x), t1 = fast_tanh(pv[it].y);
        float t2 = fast_tanh(pv[it].z), t3 = fast_tanh(pv[it].w);
        union { bf16_t b[4]; unsigned long long u; } pk;
        pk.b[0] = (bf16_t)t0; pk.b[1] = (bf16_t)t1;
        pk.b[2] = (bf16_t)t2; pk.b[3] = (bf16_t)t3;
        *reinterpret_cast<unsigned long long*>(dst + row * ROWP + lane * 4) = pk.u;
        if (nudge) {
            float s = (t0 + t1) + (t2 + t3);
            s += __shfl_down(s, 32);
            s += __shfl_down(s, 16);
            s += __shfl_down(s, 8);
            s += __shfl_down(s, 4);
            s += __shfl_down(s, 2);
            s += __shfl_down(s, 1);
            if (lane == 0) nudge[row] = s * (0.08f / 256.0f);  // DT*GSOM*mean
        }
    }
}

// K=256 GEMM, OPERAND-SWAPPED: D = Wfrag(A) x rhofrag(B).
// A-frag: lane&15 = W row (= output col), k = (lane>>4)*8+j  -> global read
// B-frag: lane&15 = rho row (= batch row), k = (lane>>4)*8+j -> LDS read
// acc[nb][mt]: nb = batch-row half (0-15 / 16-31), mt = 16-col tile.
// C layout: lane&15 = batch row, reg = consecutive out col (q*4+reg).
__device__ __forceinline__ void gemm_lds(const bf16_t* __restrict__ sa,
                                         const bf16_t* __restrict__ wg,
                                         int lane, int wv, f32x4 acc[2][4]) {
    const int r = lane & 15, q = lane >> 4;
    const bf16_t* rho0 = sa + r * ROWP + q * 8;
    const bf16_t* rho1 = rho0 + 16 * ROWP;
    const bf16_t* wp   = wg + (size_t)(wv * 64 + r) * HH + q * 8;
#pragma unroll 2
    for (int k0 = 0; k0 < HH; k0 += 32) {
        bf16x8 b0 = *reinterpret_cast<const bf16x8*>(rho0 + k0);
        bf16x8 b1 = *reinterpret_cast<const bf16x8*>(rho1 + k0);
#pragma unroll
        for (int mt = 0; mt < 4; ++mt) {
            bf16x8 wf = *reinterpret_cast<const bf16x8*>(wp + mt * 16 * HH + k0);
            acc[0][mt] = __builtin_amdgcn_mfma_f32_16x16x32_bf16(wf, b0, acc[0][mt], 0, 0, 0);
            acc[1][mt] = __builtin_amdgcn_mfma_f32_16x16x32_bf16(wf, b1, acc[1][mt], 0, 0, 0);
        }
    }
}

// Vectorized epilogue: lane (r,q) owns rows nb*16+r, cols wv*64+mt*16+q*4+(0..3).
// 8 float4 loads (batched) + 8 float4 stores per wave.
template<bool HN>
__device__ __forceinline__ void epilogue(f32x4 acc[2][4], const float* __restrict__ raw,
                                         float* __restrict__ outp, int row0, int lane, int wv,
                                         float c, const float* __restrict__ nudge) {
    const int r = lane & 15, q = lane >> 4;
    f32x4 rv[2][4];
#pragma unroll
    for (int nb = 0; nb < 2; ++nb) {
        const size_t off = (size_t)(row0 + nb * 16 + r) * HH + wv * 64 + q * 4;
#pragma unroll
        for (int mt = 0; mt < 4; ++mt)
            rv[nb][mt] = *reinterpret_cast<const f32x4*>(raw + off + mt * 16);
    }
#pragma unroll
    for (int nb = 0; nb < 2; ++nb) {
        float nlv = HN ? nudge[nb * 16 + r] : 0.0f;
        const size_t off = (size_t)(row0 + nb * 16 + r) * HH + wv * 64 + q * 4;
#pragma unroll
        for (int mt = 0; mt < 4; ++mt) {
            f32x4 o;
#pragma unroll
            for (int j = 0; j < 4; ++j) {
                o[j] = acc[nb][mt][j] + c * rv[nb][mt][j];
                if (HN) o[j] += nlv;
            }
            *reinterpret_cast<f32x4*>(outp + off + mt * 16) = o;
        }
    }
}

struct WPtrs { const float* p[9]; };

// Pre-scale + convert the 9 weight matrices to bf16 into d_ws.
// order g: 0 wpf0(.1) 1 wpf1(.1) 2 wpf2(.1) 3 wpb0(.08) 4 wpb1(.08)
//          5 wip0(.1) 6 wip1(.1) 7 wpi0(.08) 8 wpi1(.08)
__global__ void prep_w(WPtrs wp, bf16_t* __restrict__ out) {
    const float scales[9] = {0.1f, 0.1f, 0.1f, 0.08f, 0.08f, 0.1f, 0.1f, 0.08f, 0.08f};
    int g  = blockIdx.x >> 6;
    int bi = blockIdx.x & 63;
    float sc = scales[g];
    int idx = (bi * 256 + threadIdx.x) * 4;
    float4 v = *reinterpret_cast<const float4*>(wp.p[g] + idx);
    union { bf16_t b[4]; unsigned long long u; } pk;
    pk.b[0] = (bf16_t)(v.x * sc); pk.b[1] = (bf16_t)(v.y * sc);
    pk.b[2] = (bf16_t)(v.z * sc); pk.b[3] = (bf16_t)(v.w * sc);
    *reinterpret_cast<unsigned long long*>(out + (size_t)g * 65536 + idx) = pk.u;
}

#define ZACC(A_)                                                               \
    do {                                                                       \
        _Pragma("unroll")                                                      \
        for (int m_ = 0; m_ < 2; ++m_)                                         \
            _Pragma("unroll")                                                  \
            for (int nt_ = 0; nt_ < 4; ++nt_) A_[m_][nt_] = z;                 \
    } while (0)

__global__ __launch_bounds__(256, 4) void dendritic_main(
    const float* __restrict__ data, const float* __restrict__ s0,
    const float* __restrict__ s1,   const float* __restrict__ s2,
    const float* __restrict__ i0,   const float* __restrict__ i1,
    const bf16_t* __restrict__ wws, float* __restrict__ out)
{
    __shared__ bf16_t slA[TILE_ELEMS];   // rs1, resident (3 uses)
    __shared__ bf16_t slB[TILE_ELEMS];   // streaming: rd, ri0, rs2, ri1, rs0
    __shared__ float  sn0[32];           // 0.08*mean_row(rs1)
    __shared__ float  sn1[32];           // 0.08*mean_row(rs2)

    const int tid = threadIdx.x, lane = tid & 63, wv = tid >> 6;
    const int row0 = blockIdx.x * BM;

    // ---- prologue: rs1 -> slA (+n0), rd -> slB (no acc live yet)
    {
        float4 pA[8], pB[8];
        stage_issue(s1,   row0, lane, wv, pA);
        stage_issue(data, row0, lane, wv, pB);
        stage_commit(slA, lane, wv, pA, sn0);
        stage_commit(slB, lane, wv, pB, nullptr);
    }
    __syncthreads();

    f32x4 acc[2][4];                     // the ONLY accumulator array
    const f32x4 z = {0.f, 0.f, 0.f, 0.f};
    float4 pv[8];                        // the ONLY prefetch array

    // ===== P1: slB = rd; prefetch ri0 =====
    stage_issue(i0, row0, lane, wv, pv);
    ZACC(acc);
    gemm_lds(slB, wws + 0 * 65536, lane, wv, acc);    // rd  @ wpf0   (s0 chain)
    gemm_lds(slA, wws + 3 * 65536, lane, wv, acc);    // rs1 @ wpb0
    BARX();
    stage_commit(slB, lane, wv, pv, nullptr);         // slB = ri0
    BARX();

    // ===== P2: slB = ri0; prefetch rs2 =====
    stage_issue(s2, row0, lane, wv, pv);
    gemm_lds(slB, wws + 7 * 65536, lane, wv, acc);    // ri0 @ wpi0
    epilogue<false>(acc, s0, out + 0 * BHTOT, row0, lane, wv, 0.81f, nullptr); // out_s0
    ZACC(acc);
    gemm_lds(slA, wws + 2 * 65536, lane, wv, acc);    // rs1 @ wpf2
    epilogue<false>(acc, s2, out + 2 * BHTOT, row0, lane, wv, 0.89f, nullptr); // out_s2
    BARX();
    stage_commit(slB, lane, wv, pv, sn1);             // slB = rs2 (+n1)
    BARX();

    // ===== P3: slB = rs2; prefetch ri1 =====
    stage_issue(i1, row0, lane, wv, pv);
    ZACC(acc);
    gemm_lds(slB, wws + 4 * 65536, lane, wv, acc);    // rs2 @ wpb1   (s1 chain)
    BARX();
    stage_commit(slB, lane, wv, pv, nullptr);         // slB = ri1
    BARX();

    // ===== P4: slB = ri1; prefetch rs0 =====
    stage_issue(s0, row0, lane, wv, pv);
    gemm_lds(slB, wws + 8 * 65536, lane, wv, acc);    // ri1 @ wpi1   (s1 chain)
    BARX();
    stage_commit(slB, lane, wv, pv, nullptr);         // slB = rs0
    BARX();

    // ===== P5: slB = rs0; no prefetch (pv free) =====
    gemm_lds(slB, wws + 1 * 65536, lane, wv, acc);    // rs0 @ wpf1   (s1 done)
    epilogue<false>(acc, s1, out + 1 * BHTOT, row0, lane, wv, 0.81f, nullptr); // out_s1
    ZACC(acc);
    gemm_lds(slA, wws + 6 * 65536, lane, wv, acc);    // rs1 @ wip1
    epilogue<true>(acc, i1, out + 4 * BHTOT, row0, lane, wv, 0.81f, sn1);      // out_i1
    ZACC(acc);
    gemm_lds(slB, wws + 5 * 65536, lane, wv, acc);    // rs0 @ wip0
    epilogue<true>(acc, i0, out + 3 * BHTOT, row0, lane, wv, 0.81f, sn0);      // out_i0
}

extern "C" void kernel_launch(void* const* d_in, const int* in_sizes, int n_in,
                              void* d_out, int out_size, void* d_ws, size_t ws_size,
                              hipStream_t stream) {
    const float* data = (const float*)d_in[0];
    const float* s0   = (const float*)d_in[1];
    const float* s1   = (const float*)d_in[2];
    const float* s2   = (const float*)d_in[3];
    const float* i0   = (const float*)d_in[4];
    const float* i1   = (const float*)d_in[5];

    WPtrs wp;
    for (int g = 0; g < 9; ++g) wp.p[g] = (const float*)d_in[6 + g];

    bf16_t* wws = (bf16_t*)d_ws;        // 9*65536*2 = 1,179,648 B of scratch
    float*  out = (float*)d_out;

    // convert + pre-scale weights (runs every call; d_ws re-poisoned each launch)
    prep_w<<<576, 256, 0, stream>>>(wp, wws);

    // fused main: 1024 blocks x 256 threads, ~34 KB static LDS -> 4 blocks/CU
    dendritic_main<<<1024, 256, 0, stream>>>(data, s0, s1, s2, i0, i1, wws, out);
}

// Round 6
// 440.143 us; speedup vs baseline: 1.2065x; 1.0280x over previous
//
#include <hip/hip_runtime.h>
#include <hip/hip_bf16.h>

// dendriticNet fused kernel, round 6 (= round-5 design resubmitted; the
// round-5 bench died to an infra failure — "container failed twice" —
// before the kernel ever ran; same thing happened in round 1 and the
// unchanged resubmit then passed).
//
// Design: de-poison the vmcnt queue.
// r0-r4 all land at 240-290us / ~1.5TB/s across wildly different structures.
// Diagnosis: s_waitcnt vmcnt(N) retires OLDEST-FIRST -> any wait for a gemm's
// L2 W-load is gated on ALL older outstanding VMEM (the 8 HBM prefetch loads
// + epilogue stores issued earlier in the phase). Every MFMA cluster's wait
// was inflated to HBM latency + queuing => ~500k stalled cycles/wave.
// Fix vs r4 (ONLY change): stage_issue moved from phase-START to phase-END.
// Gemms now run with an empty/store-only vmcnt queue (short L2 waits);
// HBM tile latency is paid ONCE per tile at stage_commit (~900cyc x 6).
//
// out_s0 = 0.81*s0 + rd@(0.1 wpf0)^T + rs1@(0.08 wpb0)^T + ri0@(0.08 wpi0)^T
// out_i0 = 0.81*i0 + rs0@(0.1 wip0)^T + 0.08*mean_row(rs1)
// out_s1 = 0.81*s1 + rs0@(0.1 wpf1)^T + rs2@(0.08 wpb1)^T + ri1@(0.08 wpi1)^T
// out_i1 = 0.81*i1 + rs1@(0.1 wip1)^T + 0.08*mean_row(rs2)
// out_s2 = 0.89*s2 + rs1@(0.1 wpf2)^T

#define HH 256
#define BM 32
#define ROWP 264                    // padded LDS row (bf16 elems)
#define TILE_ELEMS (BM * ROWP)      // 16896 B per tile
#define BHTOT ((size_t)32768 * 256)

typedef __bf16 bf16_t;
typedef __bf16 bf16x8 __attribute__((ext_vector_type(8)));
typedef float  f32x4  __attribute__((ext_vector_type(4)));

// lgkm-only fence + barrier: does NOT drain vmcnt.
#define BARX() do { asm volatile("s_waitcnt lgkmcnt(0)" ::: "memory"); \
                    __builtin_amdgcn_s_barrier(); } while (0)

__device__ __forceinline__ float fast_tanh(float x) {
    float e = __expf(2.0f * x);
    return 1.0f - 2.0f * __builtin_amdgcn_rcpf(e + 1.0f);
}

// Issue the global loads for one BM x 256 tile (wave rows wv, wv+4, ...).
__device__ __forceinline__ void stage_issue(const float* __restrict__ src,
                                            int row0, int lane, int wv,
                                            float4 pv[8]) {
#pragma unroll
    for (int it = 0; it < 8; ++it) {
        int row = wv + it * 4;
        pv[it] = *reinterpret_cast<const float4*>(
            src + (size_t)(row0 + row) * HH + lane * 4);
    }
}

// tanh + pack + LDS write of a previously-issued tile; optional
// 0.08*mean_row into nudge[0..31].
__device__ __forceinline__ void stage_commit(bf16_t* __restrict__ dst,
                                             int lane, int wv,
                                             const float4 pv[8],
                                             float* __restrict__ nudge) {
#pragma unroll
    for (int it = 0; it < 8; ++it) {
        int row = wv + it * 4;
        float t0 = fast_tanh(pv[it].x), t1 = fast_tanh(pv[it].y);
        float t2 = fast_tanh(pv[it].z), t3 = fast_tanh(pv[it].w);
        union { bf16_t b[4]; unsigned long long u; } pk;
        pk.b[0] = (bf16_t)t0; pk.b[1] = (bf16_t)t1;
        pk.b[2] = (bf16_t)t2; pk.b[3] = (bf16_t)t3;
        *reinterpret_cast<unsigned long long*>(dst + row * ROWP + lane * 4) = pk.u;
        if (nudge) {
            float s = (t0 + t1) + (t2 + t3);
            s += __shfl_down(s, 32);
            s += __shfl_down(s, 16);
            s += __shfl_down(s, 8);
            s += __shfl_down(s, 4);
            s += __shfl_down(s, 2);
            s += __shfl_down(s, 1);
            if (lane == 0) nudge[row] = s * (0.08f / 256.0f);  // DT*GSOM*mean
        }
    }
}

// K=256 GEMM, operand-swapped: D = Wfrag(A) x rhofrag(B).
// A-frag: lane&15 = W row (= out col), k = (lane>>4)*8+j  -> global (L2) read
// B-frag: lane&15 = batch row, k = (lane>>4)*8+j          -> LDS read
// C layout: lane&15 = batch row, reg = consecutive out col (q*4+reg).
__device__ __forceinline__ void gemm_lds(const bf16_t* __restrict__ sa,
                                         const bf16_t* __restrict__ wg,
                                         int lane, int wv, f32x4 acc[2][4]) {
    const int r = lane & 15, q = lane >> 4;
    const bf16_t* rho0 = sa + r * ROWP + q * 8;
    const bf16_t* rho1 = rho0 + 16 * ROWP;
    const bf16_t* wp   = wg + (size_t)(wv * 64 + r) * HH + q * 8;
#pragma unroll 2
    for (int k0 = 0; k0 < HH; k0 += 32) {
        bf16x8 b0 = *reinterpret_cast<const bf16x8*>(rho0 + k0);
        bf16x8 b1 = *reinterpret_cast<const bf16x8*>(rho1 + k0);
#pragma unroll
        for (int mt = 0; mt < 4; ++mt) {
            bf16x8 wf = *reinterpret_cast<const bf16x8*>(wp + mt * 16 * HH + k0);
            acc[0][mt] = __builtin_amdgcn_mfma_f32_16x16x32_bf16(wf, b0, acc[0][mt], 0, 0, 0);
            acc[1][mt] = __builtin_amdgcn_mfma_f32_16x16x32_bf16(wf, b1, acc[1][mt], 0, 0, 0);
        }
    }
}

// Vectorized epilogue: lane (r,q) owns rows nb*16+r, cols wv*64+mt*16+q*4+(0..3).
template<bool HN>
__device__ __forceinline__ void epilogue(f32x4 acc[2][4], const float* __restrict__ raw,
                                         float* __restrict__ outp, int row0, int lane, int wv,
                                         float c, const float* __restrict__ nudge) {
    const int r = lane & 15, q = lane >> 4;
    f32x4 rv[2][4];
#pragma unroll
    for (int nb = 0; nb < 2; ++nb) {
        const size_t off = (size_t)(row0 + nb * 16 + r) * HH + wv * 64 + q * 4;
#pragma unroll
        for (int mt = 0; mt < 4; ++mt)
            rv[nb][mt] = *reinterpret_cast<const f32x4*>(raw + off + mt * 16);
    }
#pragma unroll
    for (int nb = 0; nb < 2; ++nb) {
        float nlv = HN ? nudge[nb * 16 + r] : 0.0f;
        const size_t off = (size_t)(row0 + nb * 16 + r) * HH + wv * 64 + q * 4;
#pragma unroll
        for (int mt = 0; mt < 4; ++mt) {
            f32x4 o;
#pragma unroll
            for (int j = 0; j < 4; ++j) {
                o[j] = acc[nb][mt][j] + c * rv[nb][mt][j];
                if (HN) o[j] += nlv;
            }
            *reinterpret_cast<f32x4*>(outp + off + mt * 16) = o;
        }
    }
}

struct WPtrs { const float* p[9]; };

// Pre-scale + convert the 9 weight matrices to bf16 into d_ws.
// order g: 0 wpf0(.1) 1 wpf1(.1) 2 wpf2(.1) 3 wpb0(.08) 4 wpb1(.08)
//          5 wip0(.1) 6 wip1(.1) 7 wpi0(.08) 8 wpi1(.08)
__global__ void prep_w(WPtrs wp, bf16_t* __restrict__ out) {
    const float scales[9] = {0.1f, 0.1f, 0.1f, 0.08f, 0.08f, 0.1f, 0.1f, 0.08f, 0.08f};
    int g  = blockIdx.x >> 6;
    int bi = blockIdx.x & 63;
    float sc = scales[g];
    int idx = (bi * 256 + threadIdx.x) * 4;
    float4 v = *reinterpret_cast<const float4*>(wp.p[g] + idx);
    union { bf16_t b[4]; unsigned long long u; } pk;
    pk.b[0] = (bf16_t)(v.x * sc); pk.b[1] = (bf16_t)(v.y * sc);
    pk.b[2] = (bf16_t)(v.z * sc); pk.b[3] = (bf16_t)(v.w * sc);
    *reinterpret_cast<unsigned long long*>(out + (size_t)g * 65536 + idx) = pk.u;
}

#define ZACC(A_)                                                               \
    do {                                                                       \
        _Pragma("unroll")                                                      \
        for (int m_ = 0; m_ < 2; ++m_)                                         \
            _Pragma("unroll")                                                  \
            for (int nt_ = 0; nt_ < 4; ++nt_) A_[m_][nt_] = z;                 \
    } while (0)

__global__ __launch_bounds__(256, 4) void dendritic_main(
    const float* __restrict__ data, const float* __restrict__ s0,
    const float* __restrict__ s1,   const float* __restrict__ s2,
    const float* __restrict__ i0,   const float* __restrict__ i1,
    const bf16_t* __restrict__ wws, float* __restrict__ out)
{
    __shared__ bf16_t slA[TILE_ELEMS];   // rs1, resident (3 uses)
    __shared__ bf16_t slB[TILE_ELEMS];   // streaming: rd, ri0, rs2, ri1, rs0
    __shared__ float  sn0[32];           // 0.08*mean_row(rs1)
    __shared__ float  sn1[32];           // 0.08*mean_row(rs2)

    const int tid = threadIdx.x, lane = tid & 63, wv = tid >> 6;
    const int row0 = blockIdx.x * BM;

    // ---- prologue: rs1 -> slA (+n0), rd -> slB
    {
        float4 pA[8], pB[8];
        stage_issue(s1,   row0, lane, wv, pA);
        stage_issue(data, row0, lane, wv, pB);
        stage_commit(slA, lane, wv, pA, sn0);
        stage_commit(slB, lane, wv, pB, nullptr);
    }
    __syncthreads();                     // drains everything: gemms start clean

    f32x4 acc[2][4];                     // the ONLY accumulator array
    const f32x4 z = {0.f, 0.f, 0.f, 0.f};
    float4 pv[8];                        // the ONLY prefetch array

    // ===== P1: slB = rd ===== (gemms CLEAN; issue ri0 only after them)
    ZACC(acc);
    gemm_lds(slB, wws + 0 * 65536, lane, wv, acc);    // rd  @ wpf0   (s0 chain)
    gemm_lds(slA, wws + 3 * 65536, lane, wv, acc);    // rs1 @ wpb0
    stage_issue(i0, row0, lane, wv, pv);              // HBM loads: after gemms
    BARX();
    stage_commit(slB, lane, wv, pv, nullptr);         // one vmcnt wait / tile
    BARX();

    // ===== P2: slB = ri0 =====
    gemm_lds(slB, wws + 7 * 65536, lane, wv, acc);    // ri0 @ wpi0 (clean)
    epilogue<false>(acc, s0, out + 0 * BHTOT, row0, lane, wv, 0.81f, nullptr); // out_s0
    ZACC(acc);
    gemm_lds(slA, wws + 2 * 65536, lane, wv, acc);    // rs1 @ wpf2 (store-acks only)
    epilogue<false>(acc, s2, out + 2 * BHTOT, row0, lane, wv, 0.89f, nullptr); // out_s2
    stage_issue(s2, row0, lane, wv, pv);
    BARX();
    stage_commit(slB, lane, wv, pv, sn1);             // slB = rs2 (+n1)
    BARX();

    // ===== P3: slB = rs2 =====
    ZACC(acc);
    gemm_lds(slB, wws + 4 * 65536, lane, wv, acc);    // rs2 @ wpb1   (s1 chain)
    stage_issue(i1, row0, lane, wv, pv);
    BARX();
    stage_commit(slB, lane, wv, pv, nullptr);         // slB = ri1
    BARX();

    // ===== P4: slB = ri1 =====
    gemm_lds(slB, wws + 8 * 65536, lane, wv, acc);    // ri1 @ wpi1   (s1 chain)
    stage_issue(s0, row0, lane, wv, pv);
    BARX();
    stage_commit(slB, lane, wv, pv, nullptr);         // slB = rs0
    BARX();

    // ===== P5: slB = rs0 =====
    gemm_lds(slB, wws + 1 * 65536, lane, wv, acc);    // rs0 @ wpf1   (s1 done)
    epilogue<false>(acc, s1, out + 1 * BHTOT, row0, lane, wv, 0.81f, nullptr); // out_s1
    ZACC(acc);
    gemm_lds(slA, wws + 6 * 65536, lane, wv, acc);    // rs1 @ wip1
    epilogue<true>(acc, i1, out + 4 * BHTOT, row0, lane, wv, 0.81f, sn1);      // out_i1
    ZACC(acc);
    gemm_lds(slB, wws + 5 * 65536, lane, wv, acc);    // rs0 @ wip0
    epilogue<true>(acc, i0, out + 3 * BHTOT, row0, lane, wv, 0.81f, sn0);      // out_i0
}

extern "C" void kernel_launch(void* const* d_in, const int* in_sizes, int n_in,
                              void* d_out, int out_size, void* d_ws, size_t ws_size,
                              hipStream_t stream) {
    const float* data = (const float*)d_in[0];
    const float* s0   = (const float*)d_in[1];
    const float* s1   = (const float*)d_in[2];
    const float* s2   = (const float*)d_in[3];
    const float* i0   = (const float*)d_in[4];
    const float* i1   = (const float*)d_in[5];

    WPtrs wp;
    for (int g = 0; g < 9; ++g) wp.p[g] = (const float*)d_in[6 + g];

    bf16_t* wws = (bf16_t*)d_ws;        // 9*65536*2 = 1,179,648 B of scratch
    float*  out = (float*)d_out;

    // convert + pre-scale weights (runs every call; d_ws re-poisoned each launch)
    prep_w<<<576, 256, 0, stream>>>(wp, wws);

    // fused main: 1024 blocks x 256 threads, ~34 KB static LDS -> 4 blocks/CU
    dendritic_main<<<1024, 256, 0, stream>>>(data, s0, s1, s2, i0, i1, wws, out);
}